// Round 1
// baseline (278.522 us; speedup 1.0000x reference)
//
#include <hip/hip_runtime.h>

// GNN_module: patch-conv -> deformable 27-tap sampling -> per-pixel attention -> up+1x1 conv
// Shapes: input[1,64,8,96,96] f32, flow[1,2,8,24,24], out[1,64,8,96,96] f32
// T=8, H=W=24, C=256, K=27, J = T*K = 216

typedef unsigned short ushort_t;
typedef ushort_t ushort8 __attribute__((ext_vector_type(8)));

#define POS   576            // H*W
#define M1    4608           // T*H*W
#define NSTR  264            // neigh row stride in ushorts (16B-aligned rows)

__device__ __forceinline__ ushort_t f2bf(float f) {
    unsigned u = __float_as_uint(f);
    u += 0x7fffu + ((u >> 16) & 1u);            // RNE
    return (ushort_t)(u >> 16);
}
__device__ __forceinline__ float bf2f(ushort_t u) {
    return __uint_as_float(((unsigned)u) << 16);
}

// ---------------------------------------------------------------- prep -------
// w_nodeT[k*256+o] = w_node[o*1024+k]   (k = c*16 + a*4 + b)
// WfT[k*1024 + o*16 + ab] = sum_c64 w_out[o,c64] * w_up[k,c64,ab]
// bias_tot[o] = b_out[o] + sum_c64 w_out[o,c64]*b_up[c64]
__global__ __launch_bounds__(256) void k_prep(
    const float* __restrict__ w_node, const float* __restrict__ w_up,
    const float* __restrict__ w_out, const float* __restrict__ b_up,
    const float* __restrict__ b_out,
    float* __restrict__ w_nodeT, float* __restrict__ WfT, float* __restrict__ bias_tot)
{
    __shared__ float wout_s[4096];
    int tid = threadIdx.x;
    for (int i = tid; i < 4096; i += 256) wout_s[i] = w_out[i];
    __syncthreads();
    int gid = blockIdx.x * 256 + tid;
    #pragma unroll
    for (int r = 0; r < 4; ++r) {
        int e = gid + r * 65536;                 // e < 262144
        w_nodeT[e] = w_node[((e & 255) << 10) + (e >> 8)];
        int k = e >> 10, n = e & 1023, o = n >> 4, ab = n & 15;
        const float* wo = wout_s + o * 64;
        const float* wu = w_up + (k << 10) + ab; // w_up[k*1024 + c*16 + ab]
        float s = 0.f;
        #pragma unroll 8
        for (int c = 0; c < 64; ++c) s += wo[c] * wu[c << 4];
        WfT[e] = s;
    }
    if (blockIdx.x == 0 && tid < 64) {
        float s = b_out[tid];
        const float* wo = wout_s + tid * 64;
        #pragma unroll 8
        for (int c = 0; c < 64; ++c) s += wo[c] * b_up[c];
        bias_tot[tid] = s;
    }
}

// ------------------------------------------------------------ node GEMM ------
// node_l[m*256 + o], m = t*576 + h*24 + w; M=4608, K=1024, N=256
// BM=64, BN=64, BK=32, 256 threads, 4x4 register tile
__global__ __launch_bounds__(256) void k_node(
    const float* __restrict__ input, const float* __restrict__ w_nodeT,
    const float* __restrict__ b_node, float* __restrict__ node_l)
{
    __shared__ float a_s[32 * 64];
    __shared__ float b_s[32 * 64];
    int tid = threadIdx.x;
    int m0 = blockIdx.x * 64, o0 = blockIdx.y * 64;
    int mm = tid & 63, kh = tid >> 6;            // A loader: one m, 8 k's
    int m = m0 + mm;
    int t = m / 576, hw = m % 576, h = hw / 24, w = hw % 24;
    int pbase = t * 9216 + h * 384 + w * 4;      // input[c*73728 + pbase + a*96 + b]
    int ldk = tid >> 3, ldo = (tid & 7) * 8;     // B loader
    int ty = tid >> 4, tx = tid & 15;
    float acc[4][4] = {};

    for (int k0 = 0; k0 < 1024; k0 += 32) {
        int k = k0 + kh * 8;
        int c = k >> 4, a0 = (k >> 2) & 3;       // a0 in {0,2}
        const float* ip = input + c * 73728 + pbase + a0 * 96;
        float4 fa = *(const float4*)(ip);
        float4 fb = *(const float4*)(ip + 96);
        int kl = kh * 8;
        a_s[(kl + 0) * 64 + mm] = fa.x; a_s[(kl + 1) * 64 + mm] = fa.y;
        a_s[(kl + 2) * 64 + mm] = fa.z; a_s[(kl + 3) * 64 + mm] = fa.w;
        a_s[(kl + 4) * 64 + mm] = fb.x; a_s[(kl + 5) * 64 + mm] = fb.y;
        a_s[(kl + 6) * 64 + mm] = fb.z; a_s[(kl + 7) * 64 + mm] = fb.w;
        const float* bp = w_nodeT + (k0 + ldk) * 256 + o0 + ldo;
        *(float4*)&b_s[ldk * 64 + ldo]     = *(const float4*)bp;
        *(float4*)&b_s[ldk * 64 + ldo + 4] = *(const float4*)(bp + 4);
        __syncthreads();
        #pragma unroll 8
        for (int kk = 0; kk < 32; ++kk) {
            float4 av = *(const float4*)&a_s[kk * 64 + ty * 4];
            float4 bv = *(const float4*)&b_s[kk * 64 + tx * 4];
            acc[0][0] += av.x * bv.x; acc[0][1] += av.x * bv.y; acc[0][2] += av.x * bv.z; acc[0][3] += av.x * bv.w;
            acc[1][0] += av.y * bv.x; acc[1][1] += av.y * bv.y; acc[1][2] += av.y * bv.z; acc[1][3] += av.y * bv.w;
            acc[2][0] += av.z * bv.x; acc[2][1] += av.z * bv.y; acc[2][2] += av.z * bv.z; acc[2][3] += av.z * bv.w;
            acc[3][0] += av.w * bv.x; acc[3][1] += av.w * bv.y; acc[3][2] += av.w * bv.z; acc[3][3] += av.w * bv.w;
        }
        __syncthreads();
    }
    float4 bn = *(const float4*)&b_node[o0 + tx * 4];
    #pragma unroll
    for (int i = 0; i < 4; ++i) {
        float4 v = make_float4(acc[i][0] + bn.x, acc[i][1] + bn.y, acc[i][2] + bn.z, acc[i][3] + bn.w);
        *(float4*)&node_l[(m0 + ty * 4 + i) * 256 + o0 + tx * 4] = v;
    }
}

// ------------------------------------------------------------- attention -----
// One block per spatial position (576). Dynamic LDS 132,608 B:
//   neigh[216][264] bf16, nb[8][256] f32, A_s[8][216] f32, coord arrays
__global__ __launch_bounds__(256) void k_attn(
    const float* __restrict__ node_l, const float* __restrict__ flow,
    float* __restrict__ out_l)
{
    extern __shared__ char smem[];
    ushort_t* neigh = (ushort_t*)smem;                    // 114048 B
    float* nb  = (float*)(smem + 114048);                 // 8192 B
    float* A_s = (float*)(smem + 122240);                 // 6912 B
    int*   y0s = (int*)(smem + 129152);                   // 864 B
    int*   x0s = (int*)(smem + 130016);
    float* tys = (float*)(smem + 130880);
    float* txs = (float*)(smem + 131744);                 // ends 132608

    int tid = threadIdx.x;
    int pos = blockIdx.x;
    int h = pos / 24, w = pos % 24;

    // phase 0: node_b rows (f32)
    #pragma unroll
    for (int t = 0; t < 8; ++t)
        nb[t * 256 + tid] = node_l[(t * 576 + pos) * 256 + tid];

    // phase 1: sampling coords for j = t'*27 + k
    if (tid < 216) {
        int j = tid, tt = j / 27, kk = j % 27;
        int d = 2 * (kk / 9) + 1;                         // 1,3,5
        int oy = (kk / 3) % 3 - 1, ox = kk % 3 - 1;
        float fy = flow[tt * 576 + pos];
        float fx = flow[4608 + tt * 576 + pos];
        float py = (float)(h + oy * d) + fy;
        float px = (float)(w + ox * d) + fx;
        float fy0 = floorf(py), fx0 = floorf(px);
        y0s[j] = (int)fy0; x0s[j] = (int)fx0;
        tys[j] = py - fy0;  txs[j] = px - fx0;
    }
    __syncthreads();

    // phase 2: neighbour rows -> bf16 LDS (thread = channel c)
    for (int tt = 0; tt < 8; ++tt) {
        const float* npt = node_l + tt * (576 * 256);
        #pragma unroll 3
        for (int kk = 0; kk < 27; ++kk) {
            int j = tt * 27 + kk;
            int y0 = y0s[j], x0 = x0s[j];
            float ty = tys[j], tx = txs[j];
            int y0c = min(max(y0, 0), 23), y1c = min(max(y0 + 1, 0), 23);
            int x0c = min(max(x0, 0), 23), x1c = min(max(x0 + 1, 0), 23);
            float vy0 = (y0 >= 0 && y0 < 24) ? 1.f : 0.f;
            float vy1 = (y0 >= -1 && y0 < 23) ? 1.f : 0.f;
            float vx0 = (x0 >= 0 && x0 < 24) ? 1.f : 0.f;
            float vx1 = (x0 >= -1 && x0 < 23) ? 1.f : 0.f;
            float w00 = (1.f - ty) * (1.f - tx) * vy0 * vx0;
            float w01 = (1.f - ty) * tx * vy0 * vx1;
            float w10 = ty * (1.f - tx) * vy1 * vx0;
            float w11 = ty * tx * vy1 * vx1;
            float g00 = npt[(y0c * 24 + x0c) * 256 + tid];
            float g01 = npt[(y0c * 24 + x1c) * 256 + tid];
            float g10 = npt[(y1c * 24 + x0c) * 256 + tid];
            float g11 = npt[(y1c * 24 + x1c) * 256 + tid];
            float v = w00 * g00 + w01 * g01 + w10 * g10 + w11 * g11;
            neigh[j * NSTR + tid] = f2bf(v);
        }
    }
    __syncthreads();

    // phase 3: A[t][j] = (1/216) * dot(nb[t], neigh[j]); thread tile 2t x 4j
    if (tid < 216) {
        int tg = tid / 54, jg = tid % 54;
        int t0 = tg * 2;
        const float* nb0 = nb + t0 * 256;
        const float* nb1 = nb0 + 256;
        float acc[2][4] = {};
        for (int c0 = 0; c0 < 256; c0 += 8) {
            float4 a00 = *(const float4*)&nb0[c0];
            float4 a01 = *(const float4*)&nb0[c0 + 4];
            float4 a10 = *(const float4*)&nb1[c0];
            float4 a11 = *(const float4*)&nb1[c0 + 4];
            #pragma unroll
            for (int jj = 0; jj < 4; ++jj) {
                int j = jg + 54 * jj;
                ushort8 u = *(const ushort8*)&neigh[j * NSTR + c0];
                float f0 = bf2f(u[0]), f1 = bf2f(u[1]), f2 = bf2f(u[2]), f3 = bf2f(u[3]);
                float f4 = bf2f(u[4]), f5 = bf2f(u[5]), f6 = bf2f(u[6]), f7 = bf2f(u[7]);
                acc[0][jj] += a00.x * f0 + a00.y * f1 + a00.z * f2 + a00.w * f3
                            + a01.x * f4 + a01.y * f5 + a01.z * f6 + a01.w * f7;
                acc[1][jj] += a10.x * f0 + a10.y * f1 + a10.z * f2 + a10.w * f3
                            + a11.x * f4 + a11.y * f5 + a11.z * f6 + a11.w * f7;
            }
        }
        const float sc = 1.f / 216.f;
        #pragma unroll
        for (int jj = 0; jj < 4; ++jj) {
            int j = jg + 54 * jj;
            A_s[t0 * 216 + j]       = acc[0][jj] * sc;
            A_s[(t0 + 1) * 216 + j] = acc[1][jj] * sc;
        }
    }
    __syncthreads();

    // phase 4: out[t][c] = sum_j A[t][j]*neigh[j][c]; thread = (t, 8 channels)
    {
        int t = tid >> 5, c0 = (tid & 31) * 8;
        const float* Ar = A_s + t * 216;
        float oa[8] = {};
        for (int q = 0; q < 54; ++q) {
            float4 av = *(const float4*)&Ar[q * 4];
            #pragma unroll
            for (int r = 0; r < 4; ++r) {
                int j = q * 4 + r;
                ushort8 u = *(const ushort8*)&neigh[j * NSTR + c0];
                float wv = (r == 0) ? av.x : (r == 1) ? av.y : (r == 2) ? av.z : av.w;
                oa[0] += wv * bf2f(u[0]); oa[1] += wv * bf2f(u[1]);
                oa[2] += wv * bf2f(u[2]); oa[3] += wv * bf2f(u[3]);
                oa[4] += wv * bf2f(u[4]); oa[5] += wv * bf2f(u[5]);
                oa[6] += wv * bf2f(u[6]); oa[7] += wv * bf2f(u[7]);
            }
        }
        float* op = out_l + (t * 576 + pos) * 256 + c0;
        *(float4*)op       = make_float4(oa[0], oa[1], oa[2], oa[3]);
        *(float4*)(op + 4) = make_float4(oa[4], oa[5], oa[6], oa[7]);
    }
}

// ------------------------------------------------------------ final GEMM -----
// M=4608 (t,h,w), K=256, N=1024 (n = o*16 + ab); BM=64, BN=128, BK=32, 4x8 tile
__global__ __launch_bounds__(256) void k_final(
    const float* __restrict__ out_l, const float* __restrict__ WfT,
    const float* __restrict__ bias_tot, float* __restrict__ dout)
{
    __shared__ float a_s[32 * 64];
    __shared__ float b_s[32 * 128];
    int tid = threadIdx.x;
    int m0 = blockIdx.x * 64, n0 = blockIdx.y * 128;
    int mm = tid & 63, kq = tid >> 6;
    int ldk = tid >> 3, ldn = (tid & 7) * 16;
    int ty = tid >> 4, tx = tid & 15;
    float acc[4][8] = {};

    for (int k0 = 0; k0 < 256; k0 += 32) {
        const float* ap = out_l + (m0 + mm) * 256 + k0 + kq * 8;
        float4 fa = *(const float4*)ap;
        float4 fb = *(const float4*)(ap + 4);
        int kl = kq * 8;
        a_s[(kl + 0) * 64 + mm] = fa.x; a_s[(kl + 1) * 64 + mm] = fa.y;
        a_s[(kl + 2) * 64 + mm] = fa.z; a_s[(kl + 3) * 64 + mm] = fa.w;
        a_s[(kl + 4) * 64 + mm] = fb.x; a_s[(kl + 5) * 64 + mm] = fb.y;
        a_s[(kl + 6) * 64 + mm] = fb.z; a_s[(kl + 7) * 64 + mm] = fb.w;
        const float* bp = WfT + (k0 + ldk) * 1024 + n0 + ldn;
        *(float4*)&b_s[ldk * 128 + ldn]      = *(const float4*)bp;
        *(float4*)&b_s[ldk * 128 + ldn + 4]  = *(const float4*)(bp + 4);
        *(float4*)&b_s[ldk * 128 + ldn + 8]  = *(const float4*)(bp + 8);
        *(float4*)&b_s[ldk * 128 + ldn + 12] = *(const float4*)(bp + 12);
        __syncthreads();
        #pragma unroll 4
        for (int kk = 0; kk < 32; ++kk) {
            float4 av = *(const float4*)&a_s[kk * 64 + ty * 4];
            float4 b0 = *(const float4*)&b_s[kk * 128 + tx * 8];
            float4 b1 = *(const float4*)&b_s[kk * 128 + tx * 8 + 4];
            acc[0][0] += av.x * b0.x; acc[0][1] += av.x * b0.y; acc[0][2] += av.x * b0.z; acc[0][3] += av.x * b0.w;
            acc[0][4] += av.x * b1.x; acc[0][5] += av.x * b1.y; acc[0][6] += av.x * b1.z; acc[0][7] += av.x * b1.w;
            acc[1][0] += av.y * b0.x; acc[1][1] += av.y * b0.y; acc[1][2] += av.y * b0.z; acc[1][3] += av.y * b0.w;
            acc[1][4] += av.y * b1.x; acc[1][5] += av.y * b1.y; acc[1][6] += av.y * b1.z; acc[1][7] += av.y * b1.w;
            acc[2][0] += av.z * b0.x; acc[2][1] += av.z * b0.y; acc[2][2] += av.z * b0.z; acc[2][3] += av.z * b0.w;
            acc[2][4] += av.z * b1.x; acc[2][5] += av.z * b1.y; acc[2][6] += av.z * b1.z; acc[2][7] += av.z * b1.w;
            acc[3][0] += av.w * b0.x; acc[3][1] += av.w * b0.y; acc[3][2] += av.w * b0.z; acc[3][3] += av.w * b0.w;
            acc[3][4] += av.w * b1.x; acc[3][5] += av.w * b1.y; acc[3][6] += av.w * b1.z; acc[3][7] += av.w * b1.w;
        }
        __syncthreads();
    }
    int nb_ = n0 + tx * 8;
    int o = nb_ >> 4, a0 = (nb_ >> 2) & 3;        // a0 in {0,2}
    float bias = bias_tot[o];
    #pragma unroll
    for (int i = 0; i < 4; ++i) {
        int m = m0 + ty * 4 + i;
        int t = m / 576, hw = m % 576, hh = hw / 24, ww = hw % 24;
        float* orow = dout + ((o * 8 + t) * 96 + hh * 4 + a0) * 96 + ww * 4;
        *(float4*)orow        = make_float4(acc[i][0] + bias, acc[i][1] + bias, acc[i][2] + bias, acc[i][3] + bias);
        *(float4*)(orow + 96) = make_float4(acc[i][4] + bias, acc[i][5] + bias, acc[i][6] + bias, acc[i][7] + bias);
    }
}

// ----------------------------------------------------------------------------
extern "C" void kernel_launch(void* const* d_in, const int* in_sizes, int n_in,
                              void* d_out, int out_size, void* d_ws, size_t ws_size,
                              hipStream_t stream) {
    (void)in_sizes; (void)n_in; (void)out_size; (void)ws_size;
    const float* input  = (const float*)d_in[0];
    const float* flow   = (const float*)d_in[1];
    const float* w_node = (const float*)d_in[2];
    const float* b_node = (const float*)d_in[3];
    const float* w_up   = (const float*)d_in[4];
    const float* b_up   = (const float*)d_in[5];
    const float* w_out  = (const float*)d_in[6];
    const float* b_out  = (const float*)d_in[7];
    float* dout = (float*)d_out;

    float* ws       = (float*)d_ws;                // needs ~11.6 MB
    float* node_l   = ws;                          // 1,179,648 f
    float* out_l    = ws + 1179648;                // 1,179,648 f
    float* w_nodeT  = ws + 2359296;                // 262,144 f
    float* WfT      = ws + 2621440;                // 262,144 f
    float* bias_tot = ws + 2883584;                // 64 f

    k_prep<<<256, 256, 0, stream>>>(w_node, w_up, w_out, b_up, b_out, w_nodeT, WfT, bias_tot);
    k_node<<<dim3(72, 4), 256, 0, stream>>>(input, w_nodeT, b_node, node_l);
    hipFuncSetAttribute(reinterpret_cast<const void*>(k_attn),
                        hipFuncAttributeMaxDynamicSharedMemorySize, 132608);
    k_attn<<<576, 256, 132608, stream>>>(node_l, flow, out_l);
    k_final<<<dim3(72, 8), 256, 0, stream>>>(out_l, WfT, bias_tot, dout);
}

// Round 2
// 164.569 us; speedup vs baseline: 1.6924x; 1.6924x over previous
//
#include <hip/hip_runtime.h>

// GNN_module: patch-conv -> deformable 27-tap sampling -> per-pixel attention -> up+1x1 conv
// T=8, H=W=24, C=256, K=27, J = T*K = 216 (padded 224)

typedef unsigned short ushort_t;
typedef ushort_t ushort8 __attribute__((ext_vector_type(8)));
typedef __bf16 bf16x8 __attribute__((ext_vector_type(8)));
typedef float f32x4 __attribute__((ext_vector_type(4)));
typedef unsigned int uint4v __attribute__((ext_vector_type(4)));

#define NSTR 264   // neigh row stride (ushorts): 528 B, 16B-aligned rows
#define TSTR 34    // neighT row stride (ushorts): 68 B
#define ASTR 40    // A_s row stride (ushorts): 80 B, 16B-aligned

__device__ __forceinline__ ushort_t f2bf(float f) {
    unsigned u = __float_as_uint(f);
    u += 0x7fffu + ((u >> 16) & 1u);            // RNE
    return (ushort_t)(u >> 16);
}
__device__ __forceinline__ float blo(unsigned u) { return __uint_as_float(u << 16); }
__device__ __forceinline__ float bhi(unsigned u) { return __uint_as_float(u & 0xffff0000u); }
__device__ __forceinline__ unsigned pk2(float a, float b) {
    return (unsigned)f2bf(a) | ((unsigned)f2bf(b) << 16);
}

// ---------------------------------------------------------------- prep -------
__global__ __launch_bounds__(256) void k_prep(
    const float* __restrict__ w_node, const float* __restrict__ w_up,
    const float* __restrict__ w_out, const float* __restrict__ b_up,
    const float* __restrict__ b_out,
    float* __restrict__ w_nodeT, float* __restrict__ WfT, float* __restrict__ bias_tot)
{
    __shared__ float wout_s[4096];
    int tid = threadIdx.x;
    for (int i = tid; i < 4096; i += 256) wout_s[i] = w_out[i];
    __syncthreads();
    int gid = blockIdx.x * 256 + tid;
    #pragma unroll
    for (int r = 0; r < 4; ++r) {
        int e = gid + r * 65536;
        w_nodeT[e] = w_node[((e & 255) << 10) + (e >> 8)];
        int k = e >> 10, n = e & 1023, o = n >> 4, ab = n & 15;
        const float* wo = wout_s + o * 64;
        const float* wu = w_up + (k << 10) + ab;
        float s = 0.f;
        #pragma unroll 8
        for (int c = 0; c < 64; ++c) s += wo[c] * wu[c << 4];
        WfT[e] = s;
    }
    if (blockIdx.x == 0 && tid < 64) {
        float s = b_out[tid];
        const float* wo = wout_s + tid * 64;
        #pragma unroll 8
        for (int c = 0; c < 64; ++c) s += wo[c] * b_up[c];
        bias_tot[tid] = s;
    }
}

// ------------------------------------------------------------ node GEMM ------
// node_bf[m*256 + o] (bf16), m = t*576 + h*24 + w; M=4608, K=1024, N=256
__global__ __launch_bounds__(256) void k_node(
    const float* __restrict__ input, const float* __restrict__ w_nodeT,
    const float* __restrict__ b_node, ushort_t* __restrict__ node_bf)
{
    __shared__ float a_s[32 * 64];
    __shared__ float b_s[32 * 64];
    int tid = threadIdx.x;
    int m0 = blockIdx.x * 64, o0 = blockIdx.y * 64;
    int mm = tid & 63, kh = tid >> 6;
    int m = m0 + mm;
    int t = m / 576, hw = m % 576, h = hw / 24, w = hw % 24;
    int pbase = t * 9216 + h * 384 + w * 4;
    int ldk = tid >> 3, ldo = (tid & 7) * 8;
    int ty = tid >> 4, tx = tid & 15;
    float acc[4][4] = {};

    for (int k0 = 0; k0 < 1024; k0 += 32) {
        int k = k0 + kh * 8;
        int c = k >> 4, a0 = (k >> 2) & 3;
        const float* ip = input + c * 73728 + pbase + a0 * 96;
        float4 fa = *(const float4*)(ip);
        float4 fb = *(const float4*)(ip + 96);
        int kl = kh * 8;
        a_s[(kl + 0) * 64 + mm] = fa.x; a_s[(kl + 1) * 64 + mm] = fa.y;
        a_s[(kl + 2) * 64 + mm] = fa.z; a_s[(kl + 3) * 64 + mm] = fa.w;
        a_s[(kl + 4) * 64 + mm] = fb.x; a_s[(kl + 5) * 64 + mm] = fb.y;
        a_s[(kl + 6) * 64 + mm] = fb.z; a_s[(kl + 7) * 64 + mm] = fb.w;
        const float* bp = w_nodeT + (k0 + ldk) * 256 + o0 + ldo;
        *(float4*)&b_s[ldk * 64 + ldo]     = *(const float4*)bp;
        *(float4*)&b_s[ldk * 64 + ldo + 4] = *(const float4*)(bp + 4);
        __syncthreads();
        #pragma unroll 8
        for (int kk = 0; kk < 32; ++kk) {
            float4 av = *(const float4*)&a_s[kk * 64 + ty * 4];
            float4 bv = *(const float4*)&b_s[kk * 64 + tx * 4];
            acc[0][0] += av.x * bv.x; acc[0][1] += av.x * bv.y; acc[0][2] += av.x * bv.z; acc[0][3] += av.x * bv.w;
            acc[1][0] += av.y * bv.x; acc[1][1] += av.y * bv.y; acc[1][2] += av.y * bv.z; acc[1][3] += av.y * bv.w;
            acc[2][0] += av.z * bv.x; acc[2][1] += av.z * bv.y; acc[2][2] += av.z * bv.z; acc[2][3] += av.z * bv.w;
            acc[3][0] += av.w * bv.x; acc[3][1] += av.w * bv.y; acc[3][2] += av.w * bv.z; acc[3][3] += av.w * bv.w;
        }
        __syncthreads();
    }
    float4 bn = *(const float4*)&b_node[o0 + tx * 4];
    #pragma unroll
    for (int i = 0; i < 4; ++i) {
        uint2 p;
        p.x = pk2(acc[i][0] + bn.x, acc[i][1] + bn.y);
        p.y = pk2(acc[i][2] + bn.z, acc[i][3] + bn.w);
        *(uint2*)&node_bf[(m0 + ty * 4 + i) * 256 + o0 + tx * 4] = p;
    }
}

// ------------------------------------------------------------- attention -----
// One block per spatial position (576). 256 threads = 4 waves.
// Per j-tile (32 j's x 7 tiles): sample -> A-GEMM (waves 0,1) -> out-GEMM (all).
__global__ __launch_bounds__(256) void k_attn(
    const ushort_t* __restrict__ node_bf, const float* __restrict__ flow,
    float* __restrict__ out_l)
{
    __shared__ __align__(16) int      bases[224 * 4];
    __shared__ __align__(16) float    wts[224 * 4];
    __shared__ __align__(16) ushort_t neigh[32 * NSTR];     // [j_loc][c]
    __shared__ __align__(16) ushort_t neighT[256 * TSTR];   // [c][j_loc]
    __shared__ __align__(16) ushort_t A_s[16 * ASTR];       // [t_pad16][j_loc]

    int tid  = threadIdx.x;
    int pos  = blockIdx.x;
    int h    = pos / 24, w = pos % 24;
    int lane = tid & 63, wid = tid >> 6;
    int g    = lane >> 4, r16 = lane & 15;

    // coord precompute for j = 0..223 (>=216 -> zero weights)
    if (tid < 224) {
        int j = tid;
        float w00 = 0, w01 = 0, w10 = 0, w11 = 0;
        int b00 = 0, b01 = 0, b10 = 0, b11 = 0;
        if (j < 216) {
            int tt = j / 27, kk = j - tt * 27;
            int d  = 2 * (kk / 9) + 1;
            int oy = (kk / 3) % 3 - 1, ox = kk % 3 - 1;
            float fy = flow[tt * 576 + pos];
            float fx = flow[4608 + tt * 576 + pos];
            float py = (float)(h + oy * d) + fy;
            float px = (float)(w + ox * d) + fx;
            float fy0 = floorf(py), fx0 = floorf(px);
            int y0 = (int)fy0, x0 = (int)fx0;
            float ty = py - fy0, tx = px - fx0;
            int y0c = min(max(y0, 0), 23), y1c = min(max(y0 + 1, 0), 23);
            int x0c = min(max(x0, 0), 23), x1c = min(max(x0 + 1, 0), 23);
            float vy0 = (y0 >= 0 && y0 < 24) ? 1.f : 0.f;
            float vy1 = (y0 >= -1 && y0 < 23) ? 1.f : 0.f;
            float vx0 = (x0 >= 0 && x0 < 24) ? 1.f : 0.f;
            float vx1 = (x0 >= -1 && x0 < 23) ? 1.f : 0.f;
            w00 = (1.f - ty) * (1.f - tx) * vy0 * vx0;
            w01 = (1.f - ty) * tx * vy0 * vx1;
            w10 = ty * (1.f - tx) * vy1 * vx0;
            w11 = ty * tx * vy1 * vx1;
            int base_t = tt * 576 * 256;
            b00 = base_t + (y0c * 24 + x0c) * 256;
            b01 = base_t + (y0c * 24 + x1c) * 256;
            b10 = base_t + (y1c * 24 + x0c) * 256;
            b11 = base_t + (y1c * 24 + x1c) * 256;
        }
        bases[j * 4 + 0] = b00; bases[j * 4 + 1] = b01;
        bases[j * 4 + 2] = b10; bases[j * 4 + 3] = b11;
        wts[j * 4 + 0] = w00; wts[j * 4 + 1] = w01;
        wts[j * 4 + 2] = w10; wts[j * 4 + 3] = w11;
    }
    // zero A_s (rows 8..15 stay zero forever; rows 0..7 rewritten per tile)
    for (int i = tid; i < 320; i += 256) ((unsigned*)A_s)[i] = 0;

    // nb fragments (A-operand of the first GEMM), waves 0 and 1 only.
    // lane holds nb[t=r16][c = 32*s + 8*g + e], zero for t>=8.
    bf16x8 nbf[8];
    if (wid < 2) {
        int t = r16;
        const ushort_t* src = node_bf + ((size_t)(t & 7) * 576 + pos) * 256 + g * 8;
        ushort8 uz = {};
        #pragma unroll
        for (int s = 0; s < 8; ++s) {
            ushort8 uu = *(const ushort8*)(src + s * 32);
            nbf[s] = __builtin_bit_cast(bf16x8, (t < 8) ? uu : uz);
        }
    }

    f32x4 oacc[4];
    #pragma unroll
    for (int i = 0; i < 4; ++i) oacc[i] = (f32x4){0.f, 0.f, 0.f, 0.f};

    __syncthreads();

    const int jp = tid >> 4;        // 0..15 : this thread's j-pair
    const int cb = tid & 15;        // 0..15 : this thread's 16-c block

    for (int tile = 0; tile < 7; ++tile) {
        // ---- phase 1: sample 32 j-rows into neigh + neighT (bf16)
        {
            int jl = jp * 2;
            int jA = tile * 32 + jl;
            int4   bsA = *(const int4*)&bases[jA * 4];
            int4   bsB = *(const int4*)&bases[jA * 4 + 4];
            float4 wvA = *(const float4*)&wts[jA * 4];
            float4 wvB = *(const float4*)&wts[jA * 4 + 4];
            #pragma unroll
            for (int q = 0; q < 2; ++q) {
                int c0 = cb * 16 + q * 8;
                uint4v a00 = *(const uint4v*)(node_bf + bsA.x + c0);
                uint4v a01 = *(const uint4v*)(node_bf + bsA.y + c0);
                uint4v a10 = *(const uint4v*)(node_bf + bsA.z + c0);
                uint4v a11 = *(const uint4v*)(node_bf + bsA.w + c0);
                uint4v b00 = *(const uint4v*)(node_bf + bsB.x + c0);
                uint4v b01 = *(const uint4v*)(node_bf + bsB.y + c0);
                uint4v b10 = *(const uint4v*)(node_bf + bsB.z + c0);
                uint4v b11 = *(const uint4v*)(node_bf + bsB.w + c0);
                uint4v outA, outB;
                #pragma unroll
                for (int p = 0; p < 4; ++p) {
                    float aL = wvA.x * blo(a00[p]) + wvA.y * blo(a01[p]) + wvA.z * blo(a10[p]) + wvA.w * blo(a11[p]);
                    float aH = wvA.x * bhi(a00[p]) + wvA.y * bhi(a01[p]) + wvA.z * bhi(a10[p]) + wvA.w * bhi(a11[p]);
                    float bL = wvB.x * blo(b00[p]) + wvB.y * blo(b01[p]) + wvB.z * blo(b10[p]) + wvB.w * blo(b11[p]);
                    float bH = wvB.x * bhi(b00[p]) + wvB.y * bhi(b01[p]) + wvB.z * bhi(b10[p]) + wvB.w * bhi(b11[p]);
                    outA[p] = pk2(aL, aH);
                    outB[p] = pk2(bL, bH);
                    *(unsigned*)(neighT + (c0 + 2 * p) * TSTR + jl)     = pk2(aL, bL);
                    *(unsigned*)(neighT + (c0 + 2 * p + 1) * TSTR + jl) = pk2(aH, bH);
                }
                *(uint4v*)(neigh + jl * NSTR + c0)       = outA;
                *(uint4v*)(neigh + (jl + 1) * NSTR + c0) = outB;
            }
        }
        __syncthreads();

        // ---- phase 2: A-GEMM (waves 0,1): A[t][j] = sum_c nb[t][c]*neigh[j][c]
        if (wid < 2) {
            f32x4 aacc = {0.f, 0.f, 0.f, 0.f};
            int jbase = wid * 16;
            #pragma unroll
            for (int s = 0; s < 8; ++s) {
                const ushort_t* bp = neigh + (jbase + r16) * NSTR + s * 32 + g * 8;
                bf16x8 bfrag = __builtin_bit_cast(bf16x8, *(const ushort8*)bp);
                aacc = __builtin_amdgcn_mfma_f32_16x16x32_bf16(nbf[s], bfrag, aacc, 0, 0, 0);
            }
            if (g < 2) {               // lanes holding valid t rows 0..7
                #pragma unroll
                for (int rr = 0; rr < 4; ++rr)
                    A_s[(4 * g + rr) * ASTR + jbase + r16] = f2bf(aacc[rr] * (1.f / 216.f));
            }
        }
        __syncthreads();

        // ---- phase 3: out-GEMM (all waves): out[t][c] += A[t][j] * neigh[j][c]
        {
            bf16x8 afrag = __builtin_bit_cast(bf16x8, *(const ushort8*)(A_s + r16 * ASTR + g * 8));
            #pragma unroll
            for (int i = 0; i < 4; ++i) {
                const ushort_t* tp = neighT + (wid * 64 + i * 16 + r16) * TSTR + g * 8;
                uint4v uv;
                uv.x = *(const unsigned*)(tp);
                uv.y = *(const unsigned*)(tp + 2);
                uv.z = *(const unsigned*)(tp + 4);
                uv.w = *(const unsigned*)(tp + 6);
                bf16x8 bfrag = __builtin_bit_cast(bf16x8, uv);
                oacc[i] = __builtin_amdgcn_mfma_f32_16x16x32_bf16(afrag, bfrag, oacc[i], 0, 0, 0);
            }
        }
        __syncthreads();
    }

    // epilogue: D layout col=lane&15, row=4*g+rr; valid t rows are 0..7 (g<2)
    if (g < 2) {
        #pragma unroll
        for (int i = 0; i < 4; ++i) {
            int c = wid * 64 + i * 16 + r16;
            #pragma unroll
            for (int rr = 0; rr < 4; ++rr) {
                int t = 4 * g + rr;
                out_l[((size_t)t * 576 + pos) * 256 + c] = oacc[i][rr];
            }
        }
    }
}

// ------------------------------------------------------------ final GEMM -----
// M=4608 (t,h,w), K=256, N=1024 (n = o*16 + ab); BM=64, BN=128, BK=32, 4x8 tile
__global__ __launch_bounds__(256) void k_final(
    const float* __restrict__ out_l, const float* __restrict__ WfT,
    const float* __restrict__ bias_tot, float* __restrict__ dout)
{
    __shared__ float a_s[32 * 64];
    __shared__ float b_s[32 * 128];
    int tid = threadIdx.x;
    int m0 = blockIdx.x * 64, n0 = blockIdx.y * 128;
    int mm = tid & 63, kq = tid >> 6;
    int ldk = tid >> 3, ldn = (tid & 7) * 16;
    int ty = tid >> 4, tx = tid & 15;
    float acc[4][8] = {};

    for (int k0 = 0; k0 < 256; k0 += 32) {
        const float* ap = out_l + (m0 + mm) * 256 + k0 + kq * 8;
        float4 fa = *(const float4*)ap;
        float4 fb = *(const float4*)(ap + 4);
        int kl = kq * 8;
        a_s[(kl + 0) * 64 + mm] = fa.x; a_s[(kl + 1) * 64 + mm] = fa.y;
        a_s[(kl + 2) * 64 + mm] = fa.z; a_s[(kl + 3) * 64 + mm] = fa.w;
        a_s[(kl + 4) * 64 + mm] = fb.x; a_s[(kl + 5) * 64 + mm] = fb.y;
        a_s[(kl + 6) * 64 + mm] = fb.z; a_s[(kl + 7) * 64 + mm] = fb.w;
        const float* bp = WfT + (k0 + ldk) * 1024 + n0 + ldn;
        *(float4*)&b_s[ldk * 128 + ldn]      = *(const float4*)bp;
        *(float4*)&b_s[ldk * 128 + ldn + 4]  = *(const float4*)(bp + 4);
        *(float4*)&b_s[ldk * 128 + ldn + 8]  = *(const float4*)(bp + 8);
        *(float4*)&b_s[ldk * 128 + ldn + 12] = *(const float4*)(bp + 12);
        __syncthreads();
        #pragma unroll 4
        for (int kk = 0; kk < 32; ++kk) {
            float4 av = *(const float4*)&a_s[kk * 64 + ty * 4];
            float4 b0 = *(const float4*)&b_s[kk * 128 + tx * 8];
            float4 b1 = *(const float4*)&b_s[kk * 128 + tx * 8 + 4];
            acc[0][0] += av.x * b0.x; acc[0][1] += av.x * b0.y; acc[0][2] += av.x * b0.z; acc[0][3] += av.x * b0.w;
            acc[0][4] += av.x * b1.x; acc[0][5] += av.x * b1.y; acc[0][6] += av.x * b1.z; acc[0][7] += av.x * b1.w;
            acc[1][0] += av.y * b0.x; acc[1][1] += av.y * b0.y; acc[1][2] += av.y * b0.z; acc[1][3] += av.y * b0.w;
            acc[1][4] += av.y * b1.x; acc[1][5] += av.y * b1.y; acc[1][6] += av.y * b1.z; acc[1][7] += av.y * b1.w;
            acc[2][0] += av.z * b0.x; acc[2][1] += av.z * b0.y; acc[2][2] += av.z * b0.z; acc[2][3] += av.z * b0.w;
            acc[2][4] += av.z * b1.x; acc[2][5] += av.z * b1.y; acc[2][6] += av.z * b1.z; acc[2][7] += av.z * b1.w;
            acc[3][0] += av.w * b0.x; acc[3][1] += av.w * b0.y; acc[3][2] += av.w * b0.z; acc[3][3] += av.w * b0.w;
            acc[3][4] += av.w * b1.x; acc[3][5] += av.w * b1.y; acc[3][6] += av.w * b1.z; acc[3][7] += av.w * b1.w;
        }
        __syncthreads();
    }
    int nb_ = n0 + tx * 8;
    int o = nb_ >> 4, a0 = (nb_ >> 2) & 3;
    float bias = bias_tot[o];
    #pragma unroll
    for (int i = 0; i < 4; ++i) {
        int m = m0 + ty * 4 + i;
        int t = m / 576, hw = m % 576, hh = hw / 24, ww = hw % 24;
        float* orow = dout + ((o * 8 + t) * 96 + hh * 4 + a0) * 96 + ww * 4;
        *(float4*)orow        = make_float4(acc[i][0] + bias, acc[i][1] + bias, acc[i][2] + bias, acc[i][3] + bias);
        *(float4*)(orow + 96) = make_float4(acc[i][4] + bias, acc[i][5] + bias, acc[i][6] + bias, acc[i][7] + bias);
    }
}

// ----------------------------------------------------------------------------
extern "C" void kernel_launch(void* const* d_in, const int* in_sizes, int n_in,
                              void* d_out, int out_size, void* d_ws, size_t ws_size,
                              hipStream_t stream) {
    (void)in_sizes; (void)n_in; (void)out_size; (void)ws_size;
    const float* input  = (const float*)d_in[0];
    const float* flow   = (const float*)d_in[1];
    const float* w_node = (const float*)d_in[2];
    const float* b_node = (const float*)d_in[3];
    const float* w_up   = (const float*)d_in[4];
    const float* b_up   = (const float*)d_in[5];
    const float* w_out  = (const float*)d_in[6];
    const float* b_out  = (const float*)d_in[7];
    float* dout = (float*)d_out;

    float* ws        = (float*)d_ws;                 // ~9.2 MB used
    float* out_l     = ws;                           // 1,179,648 f
    ushort_t* node_bf = (ushort_t*)(ws + 1179648);   // 1,179,648 ushorts (589,824 f)
    float* w_nodeT   = ws + 1769472;                 // 262,144 f
    float* WfT       = ws + 2031616;                 // 262,144 f
    float* bias_tot  = ws + 2293760;                 // 64 f

    k_prep<<<256, 256, 0, stream>>>(w_node, w_up, w_out, b_up, b_out, w_nodeT, WfT, bias_tot);
    k_node<<<dim3(72, 4), 256, 0, stream>>>(input, w_nodeT, b_node, node_bf);
    k_attn<<<576, 256, 0, stream>>>(node_bf, flow, out_l);
    k_final<<<dim3(72, 8), 256, 0, stream>>>(out_l, WfT, bias_tot, dout);
}

// Round 3
// 75.344 us; speedup vs baseline: 3.6967x; 2.1842x over previous
//
#include <hip/hip_runtime.h>

// GNN_module: patch-conv -> deformable 27-tap sampling -> per-pixel attention -> up+1x1 conv
// T=8, H=W=24, C=256, K=27, J=216

typedef unsigned short ushort_t;
typedef ushort_t ushort8 __attribute__((ext_vector_type(8)));
typedef __bf16 bf16x8 __attribute__((ext_vector_type(8)));
typedef float f32x4 __attribute__((ext_vector_type(4)));
typedef unsigned int uint4v __attribute__((ext_vector_type(4)));

#define NSTR 264
#define TSTR 34
#define ASTR 40

__device__ __forceinline__ ushort_t f2bf(float f) {
    unsigned u = __float_as_uint(f);
    u += 0x7fffu + ((u >> 16) & 1u);            // RNE
    return (ushort_t)(u >> 16);
}
__device__ __forceinline__ float blo(unsigned u) { return __uint_as_float(u << 16); }
__device__ __forceinline__ float bhi(unsigned u) { return __uint_as_float(u & 0xffff0000u); }
__device__ __forceinline__ unsigned pk2(float a, float b) {
    return (unsigned)f2bf(a) | ((unsigned)f2bf(b) << 16);
}
__device__ __forceinline__ void gld_lds16(const void* g, void* l) {
    __builtin_amdgcn_global_load_lds(
        (const __attribute__((address_space(1))) unsigned*)g,
        (__attribute__((address_space(3))) unsigned*)l, 16, 0, 0);
}

// ---------------------------------------------------------------- prep -------
// w_node_perm[((k>>3)*256 + n)*8 + (k&7)] = bf16(w_node[n*1024 + k])          (fragment-major)
// Wf_perm   [((k>>3)*1024 + n)*8 + (k&7)] = bf16(sum_c w_out[o,c]*w_up[k,c,ab]), n=o*16+ab
__global__ __launch_bounds__(256) void k_prep(
    const float* __restrict__ w_node, const float* __restrict__ w_up,
    const float* __restrict__ w_out, const float* __restrict__ b_up,
    const float* __restrict__ b_out,
    ushort_t* __restrict__ w_node_perm, ushort_t* __restrict__ Wf_perm,
    float* __restrict__ bias_tot)
{
    __shared__ float wout_s[4096];
    int tid = threadIdx.x;
    for (int i = tid; i < 4096; i += 256) wout_s[i] = w_out[i];
    __syncthreads();
    int gid = blockIdx.x * 256 + tid;
    #pragma unroll
    for (int r = 0; r < 4; ++r) {
        int e = gid + r * 65536;                 // e < 262144
        {   // w_node permute+cvt
            int k = e & 1023, n = e >> 10;
            w_node_perm[(((k >> 3) << 8) + n) * 8 + (k & 7)] = f2bf(w_node[n * 1024 + k]);
        }
        {   // fused up*out weight
            int n = e & 1023, k = e >> 10;       // k < 256
            int o = n >> 4, ab = n & 15;
            const float* wo = wout_s + o * 64;
            const float* wu = w_up + (k << 10) + ab;
            float s = 0.f;
            #pragma unroll 8
            for (int c = 0; c < 64; ++c) s += wo[c] * wu[c << 4];
            Wf_perm[(((k >> 3) << 10) + n) * 8 + (k & 7)] = f2bf(s);
        }
    }
    if (blockIdx.x == 0 && tid < 64) {
        float s = b_out[tid];
        const float* wo = wout_s + tid * 64;
        #pragma unroll 8
        for (int c = 0; c < 64; ++c) s += wo[c] * b_up[c];
        bias_tot[tid] = s;
    }
}

// ------------------------------------------------------------ MFMA GEMMs -----
// BM=32, BN=128, BK=64; 256 threads = 4 waves (1m x 4n), wave = 32x32 (2x2 frags)
// NODE : M=4608,K=1024,N=256, A from fp32 input patch-gather, out -> node_bf (bf16)
// FINAL: M=4608,K=256, N=1024, A from out_bf (bf16, src-swizzled gld_lds), out -> dout fp32
template<int FINAL>
__global__ __launch_bounds__(256) void k_gemm(
    const float* __restrict__ input, const ushort_t* __restrict__ a_bf,
    const ushort_t* __restrict__ w_perm, const float* __restrict__ bias,
    ushort_t* __restrict__ node_bf, float* __restrict__ dout)
{
    constexpr int KS = FINAL ? 4 : 16;
    constexpr int N  = FINAL ? 1024 : 256;
    __shared__ __align__(16) ushort_t A_lds[2][2048];   // 4 KB/buf
    __shared__ __align__(16) ushort_t B_lds[2][8192];   // 16 KB/buf
    int tid  = threadIdx.x;
    int lane = tid & 63, wid = tid >> 6;
    int g = lane >> 4, r16 = lane & 15;
    int m0 = blockIdx.x * 32, n0 = blockIdx.y * 128;

    const float*   inpA = nullptr;
    const ushort_t* finA = nullptr;
    int ldsA_slot;
    if constexpr (!FINAL) {
        int mA = tid & 31, kcA = tid >> 5;       // thread -> (m row, k-chunk)
        int m = m0 + mA;
        int t = m / 576, hw = m % 576, hh = hw / 24, ww = hw % 24;
        inpA = input + (size_t)(kcA >> 1) * 73728 + t * 9216 + hh * 384 + ww * 4 + (kcA & 1) * 192;
        ldsA_slot = (kcA * 32 + mA) * 8;         // [kc][m][8]
    } else {
        int m = m0 + (tid >> 3), q = tid & 7;    // LDS linear = [m][q][8], logical kc = q^(m&7)
        finA = a_bf + m * 256 + ((q ^ (m & 7)) * 8);
        ldsA_slot = tid * 8;
    }

    f32x4 acc[2][2];
    #pragma unroll
    for (int i = 0; i < 2; ++i)
        #pragma unroll
        for (int j = 0; j < 2; ++j) acc[i][j] = (f32x4){0.f, 0.f, 0.f, 0.f};

    float4 fa, fb;
    // prologue: stage kb=0 into buf 0
    #pragma unroll
    for (int r = 0; r < 4; ++r) {
        int s = r * 256 + tid;
        gld_lds16(w_perm + (size_t)(((s >> 7) * N + n0 + (s & 127)) * 8), &B_lds[0][s * 8]);
    }
    if constexpr (FINAL) {
        gld_lds16(finA, &A_lds[0][ldsA_slot]);
    } else {
        fa = *(const float4*)(inpA);
        fb = *(const float4*)(inpA + 96);
        uint4v p;
        p.x = pk2(fa.x, fa.y); p.y = pk2(fa.z, fa.w);
        p.z = pk2(fb.x, fb.y); p.w = pk2(fb.z, fb.w);
        *(uint4v*)&A_lds[0][ldsA_slot] = p;
    }
    __syncthreads();

    for (int kb = 0; kb < KS; ++kb) {
        int cur = kb & 1, nxt = cur ^ 1;
        bool more = (kb + 1 < KS);
        if (more) {                              // issue next-tile loads first (T3 minimum)
            #pragma unroll
            for (int r = 0; r < 4; ++r) {
                int s = r * 256 + tid;
                gld_lds16(w_perm + (size_t)((((kb + 1) * 8 + (s >> 7)) * N + n0 + (s & 127)) * 8),
                          &B_lds[nxt][s * 8]);
            }
            if constexpr (FINAL) {
                gld_lds16(finA + (kb + 1) * 64, &A_lds[nxt][ldsA_slot]);
            } else {
                fa = *(const float4*)(inpA + (size_t)(kb + 1) * 294912);
                fb = *(const float4*)(inpA + (size_t)(kb + 1) * 294912 + 96);
            }
        }
        // compute on cur
        bf16x8 af[2][2], bfr[2][2];
        #pragma unroll
        for (int mi = 0; mi < 2; ++mi)
            #pragma unroll
            for (int ks = 0; ks < 2; ++ks) {
                int idx;
                if constexpr (!FINAL) idx = ((ks * 4 + g) * 32 + mi * 16 + r16) * 8;
                else                  idx = (mi * 16 + r16) * 64 + (((ks * 4 + g) ^ (r16 & 7)) * 8);
                af[mi][ks] = __builtin_bit_cast(bf16x8, *(const ushort8*)&A_lds[cur][idx]);
            }
        #pragma unroll
        for (int ni = 0; ni < 2; ++ni)
            #pragma unroll
            for (int ks = 0; ks < 2; ++ks) {
                int idx = ((ks * 4 + g) * 128 + wid * 32 + ni * 16 + r16) * 8;
                bfr[ni][ks] = __builtin_bit_cast(bf16x8, *(const ushort8*)&B_lds[cur][idx]);
            }
        #pragma unroll
        for (int mi = 0; mi < 2; ++mi)
            #pragma unroll
            for (int ni = 0; ni < 2; ++ni)
                #pragma unroll
                for (int ks = 0; ks < 2; ++ks)
                    acc[mi][ni] = __builtin_amdgcn_mfma_f32_16x16x32_bf16(
                        af[mi][ks], bfr[ni][ks], acc[mi][ni], 0, 0, 0);
        if constexpr (!FINAL) {
            if (more) {
                uint4v p;
                p.x = pk2(fa.x, fa.y); p.y = pk2(fa.z, fa.w);
                p.z = pk2(fb.x, fb.y); p.w = pk2(fb.z, fb.w);
                *(uint4v*)&A_lds[nxt][ldsA_slot] = p;
            }
        }
        __syncthreads();
    }

    // epilogue: D layout col(n)=r16, row(m)=4g+rr
    if constexpr (!FINAL) {
        #pragma unroll
        for (int ni = 0; ni < 2; ++ni) {
            int n = n0 + wid * 32 + ni * 16 + r16;
            float bv = bias[n];
            #pragma unroll
            for (int mi = 0; mi < 2; ++mi)
                #pragma unroll
                for (int rr = 0; rr < 4; ++rr) {
                    int m = m0 + mi * 16 + 4 * g + rr;
                    node_bf[(size_t)m * 256 + n] = f2bf(acc[mi][ni][rr] + bv);
                }
        }
    } else {
        #pragma unroll
        for (int ni = 0; ni < 2; ++ni) {
            int n = n0 + wid * 32 + ni * 16 + r16;
            int o = n >> 4, aa = (n >> 2) & 3, bb = n & 3;
            float bv = bias[o];
            #pragma unroll
            for (int mi = 0; mi < 2; ++mi)
                #pragma unroll
                for (int rr = 0; rr < 4; ++rr) {
                    int m = m0 + mi * 16 + 4 * g + rr;
                    int t = m / 576, hw = m % 576, hh = hw / 24, ww = hw % 24;
                    dout[((size_t)(o * 8 + t) * 96 + hh * 4 + aa) * 96 + ww * 4 + bb]
                        = acc[mi][ni][rr] + bv;
                }
        }
    }
}

// ------------------------------------------------------------- attention -----
__global__ __launch_bounds__(256) void k_attn(
    const ushort_t* __restrict__ node_bf, const float* __restrict__ flow,
    ushort_t* __restrict__ out_bf)
{
    __shared__ __align__(16) int      bases[224 * 4];
    __shared__ __align__(16) float    wts[224 * 4];
    __shared__ __align__(16) ushort_t neigh[32 * NSTR];
    __shared__ __align__(16) ushort_t neighT[256 * TSTR];
    __shared__ __align__(16) ushort_t A_s[16 * ASTR];

    int tid  = threadIdx.x;
    int pos  = blockIdx.x;
    int h    = pos / 24, w = pos % 24;
    int lane = tid & 63, wid = tid >> 6;
    int g    = lane >> 4, r16 = lane & 15;

    if (tid < 224) {
        int j = tid;
        float w00 = 0, w01 = 0, w10 = 0, w11 = 0;
        int b00 = 0, b01 = 0, b10 = 0, b11 = 0;
        if (j < 216) {
            int tt = j / 27, kk = j - tt * 27;
            int d  = 2 * (kk / 9) + 1;
            int oy = (kk / 3) % 3 - 1, ox = kk % 3 - 1;
            float fy = flow[tt * 576 + pos];
            float fx = flow[4608 + tt * 576 + pos];
            float py = (float)(h + oy * d) + fy;
            float px = (float)(w + ox * d) + fx;
            float fy0 = floorf(py), fx0 = floorf(px);
            int y0 = (int)fy0, x0 = (int)fx0;
            float ty = py - fy0, tx = px - fx0;
            int y0c = min(max(y0, 0), 23), y1c = min(max(y0 + 1, 0), 23);
            int x0c = min(max(x0, 0), 23), x1c = min(max(x0 + 1, 0), 23);
            float vy0 = (y0 >= 0 && y0 < 24) ? 1.f : 0.f;
            float vy1 = (y0 >= -1 && y0 < 23) ? 1.f : 0.f;
            float vx0 = (x0 >= 0 && x0 < 24) ? 1.f : 0.f;
            float vx1 = (x0 >= -1 && x0 < 23) ? 1.f : 0.f;
            w00 = (1.f - ty) * (1.f - tx) * vy0 * vx0;
            w01 = (1.f - ty) * tx * vy0 * vx1;
            w10 = ty * (1.f - tx) * vy1 * vx0;
            w11 = ty * tx * vy1 * vx1;
            int base_t = tt * 576 * 256;
            b00 = base_t + (y0c * 24 + x0c) * 256;
            b01 = base_t + (y0c * 24 + x1c) * 256;
            b10 = base_t + (y1c * 24 + x0c) * 256;
            b11 = base_t + (y1c * 24 + x1c) * 256;
        }
        bases[j * 4 + 0] = b00; bases[j * 4 + 1] = b01;
        bases[j * 4 + 2] = b10; bases[j * 4 + 3] = b11;
        wts[j * 4 + 0] = w00; wts[j * 4 + 1] = w01;
        wts[j * 4 + 2] = w10; wts[j * 4 + 3] = w11;
    }
    for (int i = tid; i < 320; i += 256) ((unsigned*)A_s)[i] = 0;

    bf16x8 nbf[8];
    if (wid < 2) {
        int t = r16;
        const ushort_t* src = node_bf + ((size_t)(t & 7) * 576 + pos) * 256 + g * 8;
        ushort8 uz = {};
        #pragma unroll
        for (int s = 0; s < 8; ++s) {
            ushort8 uu = *(const ushort8*)(src + s * 32);
            nbf[s] = __builtin_bit_cast(bf16x8, (t < 8) ? uu : uz);
        }
    }

    f32x4 oacc[4];
    #pragma unroll
    for (int i = 0; i < 4; ++i) oacc[i] = (f32x4){0.f, 0.f, 0.f, 0.f};

    __syncthreads();

    const int jp = tid >> 4;
    const int cb = tid & 15;

    for (int tile = 0; tile < 7; ++tile) {
        {
            int jl = jp * 2;
            int jA = tile * 32 + jl;
            int4   bsA = *(const int4*)&bases[jA * 4];
            int4   bsB = *(const int4*)&bases[jA * 4 + 4];
            float4 wvA = *(const float4*)&wts[jA * 4];
            float4 wvB = *(const float4*)&wts[jA * 4 + 4];
            #pragma unroll
            for (int q = 0; q < 2; ++q) {
                int c0 = cb * 16 + q * 8;
                uint4v a00 = *(const uint4v*)(node_bf + bsA.x + c0);
                uint4v a01 = *(const uint4v*)(node_bf + bsA.y + c0);
                uint4v a10 = *(const uint4v*)(node_bf + bsA.z + c0);
                uint4v a11 = *(const uint4v*)(node_bf + bsA.w + c0);
                uint4v b00 = *(const uint4v*)(node_bf + bsB.x + c0);
                uint4v b01 = *(const uint4v*)(node_bf + bsB.y + c0);
                uint4v b10 = *(const uint4v*)(node_bf + bsB.z + c0);
                uint4v b11 = *(const uint4v*)(node_bf + bsB.w + c0);
                uint4v outA, outB;
                #pragma unroll
                for (int p = 0; p < 4; ++p) {
                    float aL = wvA.x * blo(a00[p]) + wvA.y * blo(a01[p]) + wvA.z * blo(a10[p]) + wvA.w * blo(a11[p]);
                    float aH = wvA.x * bhi(a00[p]) + wvA.y * bhi(a01[p]) + wvA.z * bhi(a10[p]) + wvA.w * bhi(a11[p]);
                    float bL = wvB.x * blo(b00[p]) + wvB.y * blo(b01[p]) + wvB.z * blo(b10[p]) + wvB.w * blo(b11[p]);
                    float bH = wvB.x * bhi(b00[p]) + wvB.y * bhi(b01[p]) + wvB.z * bhi(b10[p]) + wvB.w * bhi(b11[p]);
                    outA[p] = pk2(aL, aH);
                    outB[p] = pk2(bL, bH);
                    *(unsigned*)(neighT + (c0 + 2 * p) * TSTR + jl)     = pk2(aL, bL);
                    *(unsigned*)(neighT + (c0 + 2 * p + 1) * TSTR + jl) = pk2(aH, bH);
                }
                *(uint4v*)(neigh + jl * NSTR + c0)       = outA;
                *(uint4v*)(neigh + (jl + 1) * NSTR + c0) = outB;
            }
        }
        __syncthreads();

        if (wid < 2) {
            f32x4 aacc = {0.f, 0.f, 0.f, 0.f};
            int jbase = wid * 16;
            #pragma unroll
            for (int s = 0; s < 8; ++s) {
                const ushort_t* bp = neigh + (jbase + r16) * NSTR + s * 32 + g * 8;
                bf16x8 bfrag = __builtin_bit_cast(bf16x8, *(const ushort8*)bp);
                aacc = __builtin_amdgcn_mfma_f32_16x16x32_bf16(nbf[s], bfrag, aacc, 0, 0, 0);
            }
            if (g < 2) {
                #pragma unroll
                for (int rr = 0; rr < 4; ++rr)
                    A_s[(4 * g + rr) * ASTR + jbase + r16] = f2bf(aacc[rr] * (1.f / 216.f));
            }
        }
        __syncthreads();

        {
            bf16x8 afrag = __builtin_bit_cast(bf16x8, *(const ushort8*)(A_s + r16 * ASTR + g * 8));
            #pragma unroll
            for (int i = 0; i < 4; ++i) {
                const ushort_t* tp = neighT + (wid * 64 + i * 16 + r16) * TSTR + g * 8;
                uint4v uv;
                uv.x = *(const unsigned*)(tp);
                uv.y = *(const unsigned*)(tp + 2);
                uv.z = *(const unsigned*)(tp + 4);
                uv.w = *(const unsigned*)(tp + 6);
                bf16x8 bfrag = __builtin_bit_cast(bf16x8, uv);
                oacc[i] = __builtin_amdgcn_mfma_f32_16x16x32_bf16(afrag, bfrag, oacc[i], 0, 0, 0);
            }
        }
        __syncthreads();
    }

    if (g < 2) {
        #pragma unroll
        for (int i = 0; i < 4; ++i) {
            int c = wid * 64 + i * 16 + r16;
            #pragma unroll
            for (int rr = 0; rr < 4; ++rr) {
                int t = 4 * g + rr;
                out_bf[((size_t)t * 576 + pos) * 256 + c] = f2bf(oacc[i][rr]);
            }
        }
    }
}

// ----------------------------------------------------------------------------
extern "C" void kernel_launch(void* const* d_in, const int* in_sizes, int n_in,
                              void* d_out, int out_size, void* d_ws, size_t ws_size,
                              hipStream_t stream) {
    (void)in_sizes; (void)n_in; (void)out_size; (void)ws_size;
    const float* input  = (const float*)d_in[0];
    const float* flow   = (const float*)d_in[1];
    const float* w_node = (const float*)d_in[2];
    const float* b_node = (const float*)d_in[3];
    const float* w_up   = (const float*)d_in[4];
    const float* b_up   = (const float*)d_in[5];
    const float* w_out  = (const float*)d_in[6];
    const float* b_out  = (const float*)d_in[7];
    float* dout = (float*)d_out;

    char* wsb = (char*)d_ws;                           // ~5.8 MB used
    ushort_t* node_bf = (ushort_t*)wsb;                // 2,359,296 B
    ushort_t* out_bf  = (ushort_t*)(wsb + 2359296);    // 2,359,296 B
    ushort_t* w_np    = (ushort_t*)(wsb + 4718592);    //   524,288 B
    ushort_t* wf_p    = (ushort_t*)(wsb + 5242880);    //   524,288 B
    float*    bias_t  = (float*)(wsb + 5767168);       //       256 B

    k_prep<<<256, 256, 0, stream>>>(w_node, w_up, w_out, b_up, b_out, w_np, wf_p, bias_t);
    k_gemm<0><<<dim3(144, 2), 256, 0, stream>>>(input, nullptr, w_np, b_node, node_bf, nullptr);
    k_attn<<<576, 256, 0, stream>>>(node_bf, flow, out_bf);
    k_gemm<1><<<dim3(144, 8), 256, 0, stream>>>(nullptr, out_bf, wf_p, bias_t, nullptr, dout);
}

// Round 4
// 74.843 us; speedup vs baseline: 3.7214x; 1.0067x over previous
//
#include <hip/hip_runtime.h>

// GNN_module: patch-conv -> deformable 27-tap sampling -> per-pixel attention -> up+1x1 conv
// T=8, H=W=24, C=256, K=27, J=216

typedef unsigned short ushort_t;
typedef ushort_t ushort8 __attribute__((ext_vector_type(8)));
typedef __bf16 bf16x8 __attribute__((ext_vector_type(8)));
typedef __bf16 bf16x2 __attribute__((ext_vector_type(2)));
typedef float f32x4 __attribute__((ext_vector_type(4)));
typedef unsigned int uint4v __attribute__((ext_vector_type(4)));

#define NSTR 264
#define TSTR 34
#define ASTR 40

__device__ __forceinline__ ushort_t f2bf(float f) {
    __bf16 h = (__bf16)f;                        // hardware RNE cvt
    return __builtin_bit_cast(ushort_t, h);
}
__device__ __forceinline__ float blo(unsigned u) { return __uint_as_float(u << 16); }
__device__ __forceinline__ float bhi(unsigned u) { return __uint_as_float(u & 0xffff0000u); }
__device__ __forceinline__ unsigned pk2(float a, float b) {
    bf16x2 v = { (__bf16)a, (__bf16)b };         // -> v_cvt_pk_bf16_f32
    return __builtin_bit_cast(unsigned, v);
}
__device__ __forceinline__ unsigned pk2h(__bf16 a, __bf16 b) {
    bf16x2 v = { a, b };
    return __builtin_bit_cast(unsigned, v);
}
__device__ __forceinline__ void gld_lds16(const void* g, void* l) {
    __builtin_amdgcn_global_load_lds(
        (const __attribute__((address_space(1))) unsigned*)g,
        (__attribute__((address_space(3))) unsigned*)l, 16, 0, 0);
}

// ---------------------------------------------------------------- prep -------
__global__ __launch_bounds__(256) void k_prep(
    const float* __restrict__ w_node, const float* __restrict__ w_up,
    const float* __restrict__ w_out, const float* __restrict__ b_up,
    const float* __restrict__ b_out,
    ushort_t* __restrict__ w_node_perm, ushort_t* __restrict__ Wf_perm,
    float* __restrict__ bias_tot)
{
    __shared__ float wout_s[4096];
    int tid = threadIdx.x;
    for (int i = tid; i < 4096; i += 256) wout_s[i] = w_out[i];
    __syncthreads();
    int gid = blockIdx.x * 256 + tid;
    #pragma unroll
    for (int r = 0; r < 4; ++r) {
        int e = gid + r * 65536;                 // e < 262144
        {   // w_node permute+cvt
            int k = e & 1023, n = e >> 10;
            w_node_perm[(((k >> 3) << 8) + n) * 8 + (k & 7)] = f2bf(w_node[n * 1024 + k]);
        }
        {   // fused up*out weight
            int n = e & 1023, k = e >> 10;       // k < 256
            int o = n >> 4, ab = n & 15;
            const float* wo = wout_s + o * 64;
            const float* wu = w_up + (k << 10) + ab;
            float s = 0.f;
            #pragma unroll 8
            for (int c = 0; c < 64; ++c) s += wo[c] * wu[c << 4];
            Wf_perm[(((k >> 3) << 10) + n) * 8 + (k & 7)] = f2bf(s);
        }
    }
    if (blockIdx.x == 0 && tid < 64) {
        float s = b_out[tid];
        const float* wo = wout_s + tid * 64;
        #pragma unroll 8
        for (int c = 0; c < 64; ++c) s += wo[c] * b_up[c];
        bias_tot[tid] = s;
    }
}

// ------------------------------------------------------------ MFMA GEMMs -----
// BM=32, BN=128, BK=64; 256 threads = 4 waves (1m x 4n), wave = 32x32 (2x2 frags)
template<int FINAL>
__global__ __launch_bounds__(256) void k_gemm(
    const float* __restrict__ input, const ushort_t* __restrict__ a_bf,
    const ushort_t* __restrict__ w_perm, const float* __restrict__ bias,
    ushort_t* __restrict__ node_bf, float* __restrict__ dout)
{
    constexpr int KS = FINAL ? 4 : 16;
    constexpr int N  = FINAL ? 1024 : 256;
    __shared__ __align__(16) ushort_t A_lds[2][2048];
    __shared__ __align__(16) ushort_t B_lds[2][8192];
    int tid  = threadIdx.x;
    int lane = tid & 63, wid = tid >> 6;
    int g = lane >> 4, r16 = lane & 15;
    int m0 = blockIdx.x * 32, n0 = blockIdx.y * 128;

    const float*   inpA = nullptr;
    const ushort_t* finA = nullptr;
    int ldsA_slot;
    if constexpr (!FINAL) {
        int mA = tid & 31, kcA = tid >> 5;
        int m = m0 + mA;
        int t = m / 576, hw = m % 576, hh = hw / 24, ww = hw % 24;
        inpA = input + (size_t)(kcA >> 1) * 73728 + t * 9216 + hh * 384 + ww * 4 + (kcA & 1) * 192;
        ldsA_slot = (kcA * 32 + mA) * 8;
    } else {
        int m = m0 + (tid >> 3), q = tid & 7;
        finA = a_bf + m * 256 + ((q ^ (m & 7)) * 8);
        ldsA_slot = tid * 8;
    }

    f32x4 acc[2][2];
    #pragma unroll
    for (int i = 0; i < 2; ++i)
        #pragma unroll
        for (int j = 0; j < 2; ++j) acc[i][j] = (f32x4){0.f, 0.f, 0.f, 0.f};

    float4 fa, fb;
    #pragma unroll
    for (int r = 0; r < 4; ++r) {
        int s = r * 256 + tid;
        gld_lds16(w_perm + (size_t)(((s >> 7) * N + n0 + (s & 127)) * 8), &B_lds[0][s * 8]);
    }
    if constexpr (FINAL) {
        gld_lds16(finA, &A_lds[0][ldsA_slot]);
    } else {
        fa = *(const float4*)(inpA);
        fb = *(const float4*)(inpA + 96);
        uint4v p;
        p.x = pk2(fa.x, fa.y); p.y = pk2(fa.z, fa.w);
        p.z = pk2(fb.x, fb.y); p.w = pk2(fb.z, fb.w);
        *(uint4v*)&A_lds[0][ldsA_slot] = p;
    }
    __syncthreads();

    for (int kb = 0; kb < KS; ++kb) {
        int cur = kb & 1, nxt = cur ^ 1;
        bool more = (kb + 1 < KS);
        if (more) {
            #pragma unroll
            for (int r = 0; r < 4; ++r) {
                int s = r * 256 + tid;
                gld_lds16(w_perm + (size_t)((((kb + 1) * 8 + (s >> 7)) * N + n0 + (s & 127)) * 8),
                          &B_lds[nxt][s * 8]);
            }
            if constexpr (FINAL) {
                gld_lds16(finA + (kb + 1) * 64, &A_lds[nxt][ldsA_slot]);
            } else {
                fa = *(const float4*)(inpA + (size_t)(kb + 1) * 294912);
                fb = *(const float4*)(inpA + (size_t)(kb + 1) * 294912 + 96);
            }
        }
        bf16x8 af[2][2], bfr[2][2];
        #pragma unroll
        for (int mi = 0; mi < 2; ++mi)
            #pragma unroll
            for (int ks = 0; ks < 2; ++ks) {
                int idx;
                if constexpr (!FINAL) idx = ((ks * 4 + g) * 32 + mi * 16 + r16) * 8;
                else                  idx = (mi * 16 + r16) * 64 + (((ks * 4 + g) ^ (r16 & 7)) * 8);
                af[mi][ks] = __builtin_bit_cast(bf16x8, *(const ushort8*)&A_lds[cur][idx]);
            }
        #pragma unroll
        for (int ni = 0; ni < 2; ++ni)
            #pragma unroll
            for (int ks = 0; ks < 2; ++ks) {
                int idx = ((ks * 4 + g) * 128 + wid * 32 + ni * 16 + r16) * 8;
                bfr[ni][ks] = __builtin_bit_cast(bf16x8, *(const ushort8*)&B_lds[cur][idx]);
            }
        #pragma unroll
        for (int mi = 0; mi < 2; ++mi)
            #pragma unroll
            for (int ni = 0; ni < 2; ++ni)
                #pragma unroll
                for (int ks = 0; ks < 2; ++ks)
                    acc[mi][ni] = __builtin_amdgcn_mfma_f32_16x16x32_bf16(
                        af[mi][ks], bfr[ni][ks], acc[mi][ni], 0, 0, 0);
        if constexpr (!FINAL) {
            if (more) {
                uint4v p;
                p.x = pk2(fa.x, fa.y); p.y = pk2(fa.z, fa.w);
                p.z = pk2(fb.x, fb.y); p.w = pk2(fb.z, fb.w);
                *(uint4v*)&A_lds[nxt][ldsA_slot] = p;
            }
        }
        __syncthreads();
    }

    if constexpr (!FINAL) {
        #pragma unroll
        for (int ni = 0; ni < 2; ++ni) {
            int n = n0 + wid * 32 + ni * 16 + r16;
            float bv = bias[n];
            #pragma unroll
            for (int mi = 0; mi < 2; ++mi)
                #pragma unroll
                for (int rr = 0; rr < 4; ++rr) {
                    int m = m0 + mi * 16 + 4 * g + rr;
                    node_bf[(size_t)m * 256 + n] = f2bf(acc[mi][ni][rr] + bv);
                }
        }
    } else {
        #pragma unroll
        for (int ni = 0; ni < 2; ++ni) {
            int n = n0 + wid * 32 + ni * 16 + r16;
            int o = n >> 4, aa = (n >> 2) & 3, bb = n & 3;
            float bv = bias[o];
            #pragma unroll
            for (int mi = 0; mi < 2; ++mi)
                #pragma unroll
                for (int rr = 0; rr < 4; ++rr) {
                    int m = m0 + mi * 16 + 4 * g + rr;
                    int t = m / 576, hw = m % 576, hh = hw / 24, ww = hw % 24;
                    dout[((size_t)(o * 8 + t) * 96 + hh * 4 + aa) * 96 + ww * 4 + bb]
                        = acc[mi][ni][rr] + bv;
                }
        }
    }
}

// ------------------------------------------------------------- attention -----
// One block per spatial position. 256 threads = 4 waves. Per 32-j tile:
// combine(regs)->LDS -> prefetch(tile+1) -> A-GEMM -> out-GEMM (T14 pipeline).
__global__ __launch_bounds__(256) void k_attn(
    const ushort_t* __restrict__ node_bf, const float* __restrict__ flow,
    ushort_t* __restrict__ out_bf)
{
    __shared__ __align__(16) int      bases[224 * 4];
    __shared__ __align__(16) float    wts[224 * 4];
    __shared__ __align__(16) ushort_t neigh[32 * NSTR];
    __shared__ __align__(16) ushort_t neighT[256 * TSTR];
    __shared__ __align__(16) ushort_t A_s[16 * ASTR];

    int tid  = threadIdx.x;
    int pos  = blockIdx.x;
    int h    = pos / 24, w = pos % 24;
    int lane = tid & 63, wid = tid >> 6;
    int g    = lane >> 4, r16 = lane & 15;

    if (tid < 224) {
        int j = tid;
        float w00 = 0, w01 = 0, w10 = 0, w11 = 0;
        int b00 = 0, b01 = 0, b10 = 0, b11 = 0;
        if (j < 216) {
            int tt = j / 27, kk = j - tt * 27;
            int d  = 2 * (kk / 9) + 1;
            int oy = (kk / 3) % 3 - 1, ox = kk % 3 - 1;
            float fy = flow[tt * 576 + pos];
            float fx = flow[4608 + tt * 576 + pos];
            float py = (float)(h + oy * d) + fy;
            float px = (float)(w + ox * d) + fx;
            float fy0 = floorf(py), fx0 = floorf(px);
            int y0 = (int)fy0, x0 = (int)fx0;
            float ty = py - fy0, tx = px - fx0;
            int y0c = min(max(y0, 0), 23), y1c = min(max(y0 + 1, 0), 23);
            int x0c = min(max(x0, 0), 23), x1c = min(max(x0 + 1, 0), 23);
            float vy0 = (y0 >= 0 && y0 < 24) ? 1.f : 0.f;
            float vy1 = (y0 >= -1 && y0 < 23) ? 1.f : 0.f;
            float vx0 = (x0 >= 0 && x0 < 24) ? 1.f : 0.f;
            float vx1 = (x0 >= -1 && x0 < 23) ? 1.f : 0.f;
            w00 = (1.f - ty) * (1.f - tx) * vy0 * vx0;
            w01 = (1.f - ty) * tx * vy0 * vx1;
            w10 = ty * (1.f - tx) * vy1 * vx0;
            w11 = ty * tx * vy1 * vx1;
            int base_t = tt * 576 * 256;
            b00 = base_t + (y0c * 24 + x0c) * 256;
            b01 = base_t + (y0c * 24 + x1c) * 256;
            b10 = base_t + (y1c * 24 + x0c) * 256;
            b11 = base_t + (y1c * 24 + x1c) * 256;
        }
        bases[j * 4 + 0] = b00; bases[j * 4 + 1] = b01;
        bases[j * 4 + 2] = b10; bases[j * 4 + 3] = b11;
        wts[j * 4 + 0] = w00; wts[j * 4 + 1] = w01;
        wts[j * 4 + 2] = w10; wts[j * 4 + 3] = w11;
    }
    for (int i = tid; i < 320; i += 256) ((unsigned*)A_s)[i] = 0;

    // nb fragments (A-operand of the A-GEMM), waves 0/1 — pure global, issue early
    bf16x8 nbf[8];
    if (wid < 2) {
        int t = r16;
        const ushort_t* src = node_bf + ((size_t)(t & 7) * 576 + pos) * 256 + g * 8;
        ushort8 uz = {};
        #pragma unroll
        for (int s = 0; s < 8; ++s) {
            ushort8 uu = *(const ushort8*)(src + s * 32);
            nbf[s] = __builtin_bit_cast(bf16x8, (t < 8) ? uu : uz);
        }
    }

    f32x4 oacc[4];
    #pragma unroll
    for (int i = 0; i < 4; ++i) oacc[i] = (f32x4){0.f, 0.f, 0.f, 0.f};

    __syncthreads();

    const int jp = tid >> 4;        // j-pair index 0..15
    const int cb = tid & 15;        // 16-channel block 0..15

    uint4v rg[2][8];                // prefetched gather data: [q][4 taps jA, 4 taps jB]
    #define PREFETCH(TILE) {                                                   \
        int jA_ = (TILE) * 32 + jp * 2;                                        \
        int4 bsA_ = *(const int4*)&bases[jA_ * 4];                             \
        int4 bsB_ = *(const int4*)&bases[jA_ * 4 + 4];                         \
        _Pragma("unroll")                                                      \
        for (int q_ = 0; q_ < 2; ++q_) {                                       \
            int c0_ = cb * 16 + q_ * 8;                                        \
            rg[q_][0] = *(const uint4v*)(node_bf + bsA_.x + c0_);              \
            rg[q_][1] = *(const uint4v*)(node_bf + bsA_.y + c0_);              \
            rg[q_][2] = *(const uint4v*)(node_bf + bsA_.z + c0_);              \
            rg[q_][3] = *(const uint4v*)(node_bf + bsA_.w + c0_);              \
            rg[q_][4] = *(const uint4v*)(node_bf + bsB_.x + c0_);              \
            rg[q_][5] = *(const uint4v*)(node_bf + bsB_.y + c0_);              \
            rg[q_][6] = *(const uint4v*)(node_bf + bsB_.z + c0_);              \
            rg[q_][7] = *(const uint4v*)(node_bf + bsB_.w + c0_);              \
        } }

    PREFETCH(0);

    for (int tile = 0; tile < 7; ++tile) {
        // ---- combine prefetched taps -> neigh + neighT (single bf16 cvt per value)
        {
            int jA = tile * 32 + jp * 2;
            int jl = jp * 2;
            float4 wA = *(const float4*)&wts[jA * 4];
            float4 wB = *(const float4*)&wts[jA * 4 + 4];
            #pragma unroll
            for (int q = 0; q < 2; ++q) {
                int c0 = cb * 16 + q * 8;
                uint4v outA, outB;
                #pragma unroll
                for (int p = 0; p < 4; ++p) {
                    unsigned a0 = rg[q][0][p], a1 = rg[q][1][p], a2 = rg[q][2][p], a3 = rg[q][3][p];
                    unsigned b0 = rg[q][4][p], b1 = rg[q][5][p], b2 = rg[q][6][p], b3 = rg[q][7][p];
                    float aL = wA.x * blo(a0) + wA.y * blo(a1) + wA.z * blo(a2) + wA.w * blo(a3);
                    float aH = wA.x * bhi(a0) + wA.y * bhi(a1) + wA.z * bhi(a2) + wA.w * bhi(a3);
                    float bL = wB.x * blo(b0) + wB.y * blo(b1) + wB.z * blo(b2) + wB.w * blo(b3);
                    float bH = wB.x * bhi(b0) + wB.y * bhi(b1) + wB.z * bhi(b2) + wB.w * bhi(b3);
                    __bf16 cAL = (__bf16)aL, cAH = (__bf16)aH;
                    __bf16 cBL = (__bf16)bL, cBH = (__bf16)bH;
                    outA[p] = pk2h(cAL, cAH);
                    outB[p] = pk2h(cBL, cBH);
                    *(unsigned*)(neighT + (c0 + 2 * p) * TSTR + jl)     = pk2h(cAL, cBL);
                    *(unsigned*)(neighT + (c0 + 2 * p + 1) * TSTR + jl) = pk2h(cAH, cBH);
                }
                *(uint4v*)(neigh + jl * NSTR + c0)       = outA;
                *(uint4v*)(neigh + (jl + 1) * NSTR + c0) = outB;
            }
        }
        // ---- issue next tile's gathers; latency hides under GEMM phases (T14)
        if (tile < 6) PREFETCH(tile + 1);
        __syncthreads();

        // ---- A-GEMM (waves 0,1): A[t][j] = sum_c nb[t][c]*neigh[j][c]
        if (wid < 2) {
            f32x4 aacc = {0.f, 0.f, 0.f, 0.f};
            int jbase = wid * 16;
            #pragma unroll
            for (int s = 0; s < 8; ++s) {
                const ushort_t* bp = neigh + (jbase + r16) * NSTR + s * 32 + g * 8;
                bf16x8 bfrag = __builtin_bit_cast(bf16x8, *(const ushort8*)bp);
                aacc = __builtin_amdgcn_mfma_f32_16x16x32_bf16(nbf[s], bfrag, aacc, 0, 0, 0);
            }
            if (g < 2) {
                #pragma unroll
                for (int rr = 0; rr < 4; ++rr)
                    A_s[(4 * g + rr) * ASTR + jbase + r16] = f2bf(aacc[rr] * (1.f / 216.f));
            }
        }
        __syncthreads();

        // ---- out-GEMM (all waves): out[t][c] += A[t][j] * neigh[j][c]
        {
            bf16x8 afrag = __builtin_bit_cast(bf16x8, *(const ushort8*)(A_s + r16 * ASTR + g * 8));
            #pragma unroll
            for (int i = 0; i < 4; ++i) {
                const ushort_t* tp = neighT + (wid * 64 + i * 16 + r16) * TSTR + g * 8;
                uint4v uv;
                uv.x = *(const unsigned*)(tp);
                uv.y = *(const unsigned*)(tp + 2);
                uv.z = *(const unsigned*)(tp + 4);
                uv.w = *(const unsigned*)(tp + 6);
                bf16x8 bfrag = __builtin_bit_cast(bf16x8, uv);
                oacc[i] = __builtin_amdgcn_mfma_f32_16x16x32_bf16(afrag, bfrag, oacc[i], 0, 0, 0);
            }
        }
        __syncthreads();
    }
    #undef PREFETCH

    if (g < 2) {
        #pragma unroll
        for (int i = 0; i < 4; ++i) {
            int c = wid * 64 + i * 16 + r16;
            #pragma unroll
            for (int rr = 0; rr < 4; ++rr) {
                int t = 4 * g + rr;
                out_bf[((size_t)t * 576 + pos) * 256 + c] = f2bf(oacc[i][rr]);
            }
        }
    }
}

// ----------------------------------------------------------------------------
extern "C" void kernel_launch(void* const* d_in, const int* in_sizes, int n_in,
                              void* d_out, int out_size, void* d_ws, size_t ws_size,
                              hipStream_t stream) {
    (void)in_sizes; (void)n_in; (void)out_size; (void)ws_size;
    const float* input  = (const float*)d_in[0];
    const float* flow   = (const float*)d_in[1];
    const float* w_node = (const float*)d_in[2];
    const float* b_node = (const float*)d_in[3];
    const float* w_up   = (const float*)d_in[4];
    const float* b_up   = (const float*)d_in[5];
    const float* w_out  = (const float*)d_in[6];
    const float* b_out  = (const float*)d_in[7];
    float* dout = (float*)d_out;

    char* wsb = (char*)d_ws;
    ushort_t* node_bf = (ushort_t*)wsb;                // 2,359,296 B
    ushort_t* out_bf  = (ushort_t*)(wsb + 2359296);    // 2,359,296 B
    ushort_t* w_np    = (ushort_t*)(wsb + 4718592);    //   524,288 B
    ushort_t* wf_p    = (ushort_t*)(wsb + 5242880);    //   524,288 B
    float*    bias_t  = (float*)(wsb + 5767168);       //       256 B

    k_prep<<<256, 256, 0, stream>>>(w_node, w_up, w_out, b_up, b_out, w_np, wf_p, bias_t);
    k_gemm<0><<<dim3(144, 2), 256, 0, stream>>>(input, nullptr, w_np, b_node, node_bf, nullptr);
    k_attn<<<576, 256, 0, stream>>>(node_bf, flow, out_bf);
    k_gemm<1><<<dim3(144, 8), 256, 0, stream>>>(nullptr, out_bf, wf_p, bias_t, nullptr, dout);
}